// Round 5
// baseline (851.808 us; speedup 1.0000x reference)
//
#include <hip/hip_runtime.h>
#include <hip/hip_bf16.h>
#include <math.h>

// Problem constants (fixed by the reference file)
#define NPTS 262144
#define NP   128
#define DD   64
#define NWORDS (NPTS / 64)   // 4096 u64 ballot words per plane

// ---------------------------------------------------------------------------
// Prep: pack plane params to [P][12] floats (normal.xyz+offs | min.xyz | max.xyz)
// -> fused kernel reads them wave-uniformly (s_load, SMEM pipe, no LDS/barrier).
// Also zero out_feats (16384 floats) for the atomic-max pool (d_out is
// re-poisoned 0xAA before every timed launch).
// ---------------------------------------------------------------------------
__global__ __launch_bounds__(256) void prep_kernel(
    const float* __restrict__ plane_center, const float* __restrict__ plane_normal,
    const float* __restrict__ pmin, const float* __restrict__ pmax,
    float* __restrict__ packed, float* __restrict__ out_feats)
{
    const int t = threadIdx.x;
    out_feats[blockIdx.x * 256 + t] = 0.0f;          // grid = 64 blocks
    if (blockIdx.x == 0 && t < NP) {
        float n0 = plane_normal[t*3+0], n1 = plane_normal[t*3+1], n2 = plane_normal[t*3+2];
        float c0 = plane_center[t*3+0], c1 = plane_center[t*3+1], c2 = plane_center[t*3+2];
        float off = (c0*n0 + c1*n1) + c2*n2;          // matches jnp.sum order
        float4* pp = reinterpret_cast<float4*>(packed) + t * 3;
        pp[0] = make_float4(n0, n1, n2, off);
        pp[1] = make_float4(pmin[t*3+0], pmin[t*3+1], pmin[t*3+2], 0.0f);
        pp[2] = make_float4(pmax[t*3+0], pmax[t*3+1], pmax[t*3+2], 0.0f);
    }
}

// ---------------------------------------------------------------------------
// Fused per-point kernel. Round-5 changes (theory: latency/occupancy-bound):
//  - fc2/BN2/fc3/h2-store split into two j-halves: peak regs = h1[64]+acc[32]
//    (+temps) ~117 VGPR instead of h1[64]+acc[64] ~180. Per-j accumulation
//    order is unchanged -> bit-identical results.
//  - __launch_bounds__(256,4): pin VGPR<=128 -> 4 waves/SIMD (was ~3).
//  - Manual prefetch in the rolled fc1 loops (load fv[q+1] before consuming
//    fv[q]) and for mask-loop plane params: gives the scheduler a full
//    iteration (~1024 issue-cycles at 4 waves/SIMD) to cover ~900cyc HBM latency.
//  - Nontemporal stores for the 4 streamed [P,N] outputs (no reuse; avoid L2
//    pollution). h2 + bitmasks stay cacheable (pool re-reads via L2/LLC).
// K-loops stay rolled (#pragma unroll 1): round-1 lesson, 32 KB I$.
// ---------------------------------------------------------------------------
__global__ __launch_bounds__(256, 4) void fused_kernel(
    const float* __restrict__ feature, const float* __restrict__ feature_geo,
    const float* __restrict__ xyz, const float* __restrict__ centers,
    const float* __restrict__ packed,
    const float* __restrict__ w1, const float* __restrict__ b1,
    const float* __restrict__ g1, const float* __restrict__ be1,
    const float* __restrict__ m1, const float* __restrict__ v1,
    const float* __restrict__ w2, const float* __restrict__ b2,
    const float* __restrict__ g2, const float* __restrict__ be2,
    const float* __restrict__ m2, const float* __restrict__ v2,
    const float* __restrict__ w3, const float* __restrict__ b3,
    float* __restrict__ h2_out,
    float* __restrict__ out_sm, float* __restrict__ out_mask,
    float* __restrict__ out_on, float* __restrict__ out_off,
    unsigned long long* __restrict__ hitOn, unsigned long long* __restrict__ hitOff)
{
    const int t = threadIdx.x;
    const int n = blockIdx.x * 256 + t;

    // cloud coords (issue early; latency hidden under fc1)
    const float c0 = xyz[n*3+0] + centers[0];
    const float c1 = xyz[n*3+1] + centers[1];
    const float c2 = xyz[n*3+2] + centers[2];

    float acc[DD];
#pragma unroll
    for (int j = 0; j < DD; ++j) acc[j] = 0.0f;

    // fc1 first half: feature (prefetched rolled loop)
    const float4* fA = reinterpret_cast<const float4*>(feature) + (size_t)n * 16;
    const float4* fB = reinterpret_cast<const float4*>(feature_geo) + (size_t)n * 16;
    float4 nxt = fA[0];
#pragma unroll 1
    for (int q = 0; q < 16; ++q) {
        const float4 fv = nxt;
        nxt = fA[(q + 1) & 15];            // q=15 reloads fA[0]: L1 hit, harmless
        const float* wr = w1 + q * 4 * DD;
#pragma unroll
        for (int j = 0; j < DD; ++j) acc[j] = fmaf(fv.x, wr[j], acc[j]);
#pragma unroll
        for (int j = 0; j < DD; ++j) acc[j] = fmaf(fv.y, wr[DD + j], acc[j]);
#pragma unroll
        for (int j = 0; j < DD; ++j) acc[j] = fmaf(fv.z, wr[2 * DD + j], acc[j]);
#pragma unroll
        for (int j = 0; j < DD; ++j) acc[j] = fmaf(fv.w, wr[3 * DD + j], acc[j]);
    }
    // fc1 second half: feature_geo
    const float* w1b = w1 + DD * DD;
    nxt = fB[0];
#pragma unroll 1
    for (int q = 0; q < 16; ++q) {
        const float4 fv = nxt;
        nxt = fB[(q + 1) & 15];
        const float* wr = w1b + q * 4 * DD;
#pragma unroll
        for (int j = 0; j < DD; ++j) acc[j] = fmaf(fv.x, wr[j], acc[j]);
#pragma unroll
        for (int j = 0; j < DD; ++j) acc[j] = fmaf(fv.y, wr[DD + j], acc[j]);
#pragma unroll
        for (int j = 0; j < DD; ++j) acc[j] = fmaf(fv.z, wr[2 * DD + j], acc[j]);
#pragma unroll
        for (int j = 0; j < DD; ++j) acc[j] = fmaf(fv.w, wr[3 * DD + j], acc[j]);
    }
    // BN1 + ReLU -> h1 (registers; acc reused below)
    float h1[DD];
#pragma unroll
    for (int j = 0; j < DD; ++j) {
        float sc = g1[j] * (1.0f / sqrtf(v1[j] + 1e-5f));
        float h  = fmaf(acc[j] + b1[j] - m1[j], sc, be1[j]);
        h1[j] = fmaxf(h, 0.0f);
    }

    // fc2 + BN2 + ReLU + fc3 + h2 store, in two 32-wide j-halves.
    // Per-j accumulation order identical to the full-width version.
    float s = 0.0f;
    float4* o = reinterpret_cast<float4*>(h2_out) + (size_t)n * 16;
#pragma unroll 1
    for (int hh = 0; hh < 2; ++hh) {
        float a2[32];
#pragma unroll
        for (int j = 0; j < 32; ++j) a2[j] = 0.0f;
        const float* w2h = w2 + hh * 32;
#pragma unroll 1
        for (int q = 0; q < 16; ++q) {
            const float fx = h1[4*q+0], fy = h1[4*q+1], fz = h1[4*q+2], fw = h1[4*q+3];
            const float* wr = w2h + q * 4 * DD;
#pragma unroll
            for (int j = 0; j < 32; ++j) a2[j] = fmaf(fx, wr[j], a2[j]);
#pragma unroll
            for (int j = 0; j < 32; ++j) a2[j] = fmaf(fy, wr[DD + j], a2[j]);
#pragma unroll
            for (int j = 0; j < 32; ++j) a2[j] = fmaf(fz, wr[2 * DD + j], a2[j]);
#pragma unroll
            for (int j = 0; j < 32; ++j) a2[j] = fmaf(fw, wr[3 * DD + j], a2[j]);
        }
#pragma unroll
        for (int j = 0; j < 32; ++j) {
            const int jj = hh * 32 + j;
            float sc = g2[jj] * (1.0f / sqrtf(v2[jj] + 1e-5f));
            float h  = fmaf(a2[j] + b2[jj] - m2[jj], sc, be2[jj]);
            h = fmaxf(h, 0.0f);
            a2[j] = h;
            s = fmaf(h, w3[jj], s);
        }
#pragma unroll
        for (int q = 0; q < 8; ++q)
            o[hh * 8 + q] = make_float4(a2[4*q+0], a2[4*q+1], a2[4*q+2], a2[4*q+3]);
    }
    s += b3[0];
    const float score = fmaxf(s, 0.0f);

    // sigmoid(score) > 0.5 via XLA-style logistic expansion (score >= 0)
    const bool on  = (0.5f + 0.5f * tanhf(0.5f * score)) > 0.5f;
    const int lane = t & 63;
    const int word = n >> 6;

    const float4* pp = reinterpret_cast<const float4*>(packed);
    float4 nrm = pp[0], mn = pp[1], mx = pp[2];
#pragma unroll 1
    for (int p = 0; p < NP; ++p) {
        const int pn = ((p + 1) & 127) * 3;          // prefetch next plane's params
        float4 nrmN = pp[pn + 0];
        float4 mnN  = pp[pn + 1];
        float4 mxN  = pp[pn + 2];
        float d = fabsf(fmaf(c2, nrm.z, fmaf(c1, nrm.y, c0 * nrm.x)) - nrm.w);
        bool ok0 = (mx.x == 0.0f) | ((c0 >= mn.x) & (c0 < mx.x));
        bool ok1 = (mx.y == 0.0f) | ((c1 >= mn.y) & (c1 < mx.y));
        bool ok2 = (mx.z == 0.0f) | ((c2 >= mn.z) & (c2 < mx.z));
        bool mk  = ok0 & ok1 & ok2 & (d < 0.1f);
        size_t idx = (size_t)p * NPTS + n;
        bool mon  = mk & on;
        bool moff = mk & (!on);
        __builtin_nontemporal_store(mk ? score : 0.0f, &out_sm[idx]);
        __builtin_nontemporal_store(mk ? 1.0f : 0.0f,  &out_mask[idx]);
        __builtin_nontemporal_store(mon ? 1.0f : 0.0f, &out_on[idx]);
        __builtin_nontemporal_store(moff ? 1.0f : 0.0f,&out_off[idx]);
        unsigned long long bOn  = __ballot(mon);
        unsigned long long bOff = __ballot(moff);
        if (lane == 0) {
            hitOn [(size_t)p * NWORDS + word] = bOn;
            hitOff[(size_t)p * NWORDS + word] = bOff;
        }
        nrm = nrmN; mn = mnN; mx = mxN;
    }
}

// ---------------------------------------------------------------------------
// Pool: masked max of h2 per plane, register-accumulated per block, then
// atomicMax(int) into out_feats (non-negative IEEE floats compare as signed
// ints; h2 >= 0; zero-init by prep -> exact where(any,max,0) semantics).
// Wave w owns planes [32w,32w+32); lane = dim; hit loop is wave-uniform.
// tile[n*64+lane]: 2-way bank alias = free (m136).
// ---------------------------------------------------------------------------
__global__ __launch_bounds__(256) void pool_kernel(
    const float* __restrict__ h2,
    const unsigned long long* __restrict__ hitOn,
    const unsigned long long* __restrict__ hitOff,
    int* __restrict__ out_feats_i)
{
    __shared__ float tile[128 * DD];                 // 32 KB
    __shared__ unsigned long long bm[2][NP][2];      // 4 KB
    const int t = threadIdx.x;
    const int lane = t & 63;
    const int wv = t >> 6;

    float accOn[32], accOff[32];
#pragma unroll
    for (int i = 0; i < 32; ++i) { accOn[i] = 0.0f; accOff[i] = 0.0f; }

    for (int cc = 0; cc < 4; ++cc) {
        const int chunk = blockIdx.x * 4 + cc;       // 0..2047
        const int base  = chunk * 128;
        const float4* src = reinterpret_cast<const float4*>(h2 + (size_t)base * DD);
        float4* dst = reinterpret_cast<float4*>(tile);
#pragma unroll
        for (int q = 0; q < 8; ++q) dst[t + q * 256] = src[t + q * 256];
        {
            const int p = t & 127;
            const int half = t >> 7;
            const unsigned long long* hsrc = half ? hitOff : hitOn;
            const int w0 = chunk * 2;
            bm[half][p][0] = hsrc[(size_t)p * NWORDS + w0 + 0];
            bm[half][p][1] = hsrc[(size_t)p * NWORDS + w0 + 1];
        }
        __syncthreads();

#pragma unroll
        for (int i = 0; i < 32; ++i) {
            const int p = wv * 32 + i;
            unsigned long long m;
            m = bm[0][p][0];
            while (m) { int nn = __builtin_ctzll(m); m &= m - 1;
                        accOn[i]  = fmaxf(accOn[i],  tile[nn * DD + lane]); }
            m = bm[0][p][1];
            while (m) { int nn = __builtin_ctzll(m); m &= m - 1;
                        accOn[i]  = fmaxf(accOn[i],  tile[(64 + nn) * DD + lane]); }
            m = bm[1][p][0];
            while (m) { int nn = __builtin_ctzll(m); m &= m - 1;
                        accOff[i] = fmaxf(accOff[i], tile[nn * DD + lane]); }
            m = bm[1][p][1];
            while (m) { int nn = __builtin_ctzll(m); m &= m - 1;
                        accOff[i] = fmaxf(accOff[i], tile[(64 + nn) * DD + lane]); }
        }
        __syncthreads();
    }
#pragma unroll
    for (int i = 0; i < 32; ++i) {
        const int p = wv * 32 + i;
        if (accOn[i]  != 0.0f) atomicMax(&out_feats_i[p * DD + lane],            __float_as_int(accOn[i]));
        if (accOff[i] != 0.0f) atomicMax(&out_feats_i[NP * DD + p * DD + lane],  __float_as_int(accOff[i]));
    }
}

extern "C" void kernel_launch(void* const* d_in, const int* in_sizes, int n_in,
                              void* d_out, int out_size, void* d_ws, size_t ws_size,
                              hipStream_t stream) {
    const float* feature      = (const float*)d_in[0];
    const float* feature_geo  = (const float*)d_in[1];
    const float* xyz          = (const float*)d_in[2];
    const float* centers      = (const float*)d_in[3];
    const float* plane_center = (const float*)d_in[4];
    const float* plane_normal = (const float*)d_in[5];
    const float* pmin         = (const float*)d_in[6];
    const float* pmax         = (const float*)d_in[7];
    const float* w1 = (const float*)d_in[8];
    const float* b1 = (const float*)d_in[9];
    const float* g1 = (const float*)d_in[10];
    const float* be1 = (const float*)d_in[11];
    const float* m1 = (const float*)d_in[12];
    const float* v1 = (const float*)d_in[13];
    const float* w2 = (const float*)d_in[14];
    const float* b2 = (const float*)d_in[15];
    const float* g2 = (const float*)d_in[16];
    const float* be2 = (const float*)d_in[17];
    const float* m2 = (const float*)d_in[18];
    const float* v2 = (const float*)d_in[19];
    const float* w3 = (const float*)d_in[20];
    const float* b3 = (const float*)d_in[21];

    float* out = (float*)d_out;
    const size_t PN = (size_t)NP * NPTS;
    float* out_sm    = out;
    float* out_mask  = out + PN;
    float* out_on    = out + 2 * PN;
    float* out_off   = out + 3 * PN;
    float* out_feats = out + 4 * PN;

    // workspace carve (~73 MB)
    float* h2     = (float*)d_ws;                                // N*64 f32 (64 MB)
    unsigned long long* hitOn  = (unsigned long long*)(h2 + (size_t)NPTS * DD);
    unsigned long long* hitOff = hitOn + (size_t)NP * NWORDS;
    float* packed = (float*)(hitOff + (size_t)NP * NWORDS);      // P*12 f32

    prep_kernel<<<64, 256, 0, stream>>>(
        plane_center, plane_normal, pmin, pmax, packed, out_feats);
    fused_kernel<<<NPTS / 256, 256, 0, stream>>>(
        feature, feature_geo, xyz, centers, packed,
        w1, b1, g1, be1, m1, v1, w2, b2, g2, be2, m2, v2, w3, b3,
        h2, out_sm, out_mask, out_on, out_off, hitOn, hitOff);
    pool_kernel<<<512, 256, 0, stream>>>(h2, hitOn, hitOff, (int*)out_feats);
}